// Round 14
// baseline (130.201 us; speedup 1.0000x reference)
//
#include <hip/hip_runtime.h>
#include <hip/hip_bf16.h>

// TripletBatchHardLoss: N=8192, D=256, fp32 embeddings (L2-normalized), int32 labels.
// Normalized -> pdist monotone DECREASING in dot:
//   hard_negative = max dot over negs, hard_positive = min dot over poss (diag dot~1 safe).
// R14: shared-A dual-tile blocks. 512 threads (8 waves); block = strip i + tile pair
// (j0=i+2p, j1=j0+1 clamped; 1056 blocks, R5-verified enumeration; dup idempotent).
// Per kt: stage A(128x32)=8KB ONCE + B0 + B1 (24KB vs 32KB for two R13 blocks);
// waves 0-3 compute tile0, waves 4-7 tile1 (per-wave state identical to R13, ~84 VGPR).
// Double-buffered (48KB LDS -> 3 blocks/CU at VGPR<=85, else 2 -> 16-24 waves/CU).
// Per-wave 3 DMAs/kt -> fine drain vmcnt(3). No launch_bounds min-waves (R7/R10 trap:
// (256,4)=64 VGPR spills, (256,5)=48 disaster). No __threadfence in wide kernels (R11).

#define NS 8192
#define DD 256
#define EPS_PD 1e-12f
#define BIGF 1e30f

typedef unsigned short u16;
typedef unsigned int u32;
typedef short short8 __attribute__((ext_vector_type(8)));
typedef float f32x4 __attribute__((ext_vector_type(4)));

typedef const __attribute__((address_space(1))) u32 glb_u32;
typedef __attribute__((address_space(3))) u32 lds_u32;

__device__ __forceinline__ void async16(const void* g, void* l) {
    __builtin_amdgcn_global_load_lds((glb_u32*)g, (lds_u32*)l, 16, 0, 0);
}

// order-preserving float <-> uint key (unsigned compare == float compare)
__device__ __forceinline__ u32 fkey(float f) {
    u32 b = __float_as_uint(f);
    return (b & 0x80000000u) ? ~b : (b | 0x80000000u);
}
__device__ __forceinline__ float unkey(u32 k) {
    u32 b = (k & 0x80000000u) ? (k ^ 0x80000000u) : ~k;
    return __uint_as_float(b);
}

__device__ __forceinline__ u16 f2bf_rne(float f) {
    u32 b = __float_as_uint(f);
    b += 0x7FFFu + ((b >> 16) & 1u);
    return (u16)(b >> 16);
}

// DPP lane-move within 16-lane rows (reduction groups are exactly DPP rows)
template <int CTRL>
__device__ __forceinline__ float dpp_mov(float x) {
    return __int_as_float(
        __builtin_amdgcn_update_dpp(0, __float_as_int(x), CTRL, 0xF, 0xF, true));
}

// ---------------- kernel 1: fp32 -> bf16, row sum-of-squares, init keys ----------------
__global__ __launch_bounds__(256) void prep_kernel(
    const float* __restrict__ e, u16* __restrict__ ebf, float* __restrict__ sq,
    u32* __restrict__ mxk, u32* __restrict__ mnk, float* __restrict__ out) {
    const int tid = blockIdx.x * 256 + threadIdx.x;   // 2048 blocks
    const int row = tid >> 6, t = tid & 63;           // one wave per row
    float4 v = ((const float4*)(e + (size_t)row * DD))[t];
    ushort4 u;
    u.x = f2bf_rne(v.x); u.y = f2bf_rne(v.y); u.z = f2bf_rne(v.z); u.w = f2bf_rne(v.w);
    ((ushort4*)(ebf + (size_t)row * DD))[t] = u;
    float s = v.x * v.x + v.y * v.y + v.z * v.z + v.w * v.w;
    for (int o = 32; o; o >>= 1) s += __shfl_down(s, o);
    if (t == 0) {
        sq[row] = s;
        mxk[row] = 0u;            // sentinel for unsigned max
        mnk[row] = 0xFFFFFFFFu;   // sentinel for unsigned min
        if (row == 0) out[0] = 0.0f;
    }
}

// -------- kernel 2: shared-A dual-tile dbuf dot-GEMM + two-sided masked reduction --------
__global__ __launch_bounds__(512) void tile_kernel(
    const u16* __restrict__ ebf, const int* __restrict__ labels,
    u32* __restrict__ mxk, u32* __restrict__ mnk) {
    // 16B chunk (row,c) at slot row*4 + (c ^ ((row>>2)&3)); 4096 u16 = one 128x32 tile
    __shared__ __attribute__((aligned(16))) u16 lds_a[2][4096];        // 2 x 8 KB
    __shared__ __attribute__((aligned(16))) u16 lds_b[2][2][4096];     // [tile][buf], 32 KB

    // decode block -> (strip i, pair p); strip i has (65-i)>>1 pairs; sum = 1056
    const int t = blockIdx.x;
    int i = 0, base = 0;
    while (t >= base + ((65 - i) >> 1)) { base += (65 - i) >> 1; ++i; }
    const int p = t - base;
    const int j0t = i + 2 * p;
    const int j1t = (j0t + 1 < 64) ? j0t + 1 : j0t;   // clamp: duplicate is idempotent
    const int bi = i * 128;
    const int bj0 = j0t * 128, bj1 = j1t * 128;

    const int tid = threadIdx.x;                 // 0..511
    const int lane = tid & 63, wid = tid >> 6;   // 8 waves
    const int tsel = wid >> 2;                   // tile group 0/1
    const int wm = (wid >> 1) & 1, wn = wid & 1;
    const int l15 = lane & 15, q = lane >> 4;
    const int bjw = tsel ? bj1 : bj0;

    // staging: wave wid owns chunk wid (slots [wid*64, wid*64+64)) of EACH of A, B0, B1
    const int slot = wid * 64 + lane;
    const int r = slot >> 2, c = (slot & 3) ^ ((r >> 2) & 3);
    const u16* gA = ebf + (size_t)(bi + r) * DD + c * 8;
    const u16* gB0 = ebf + (size_t)(bj0 + r) * DD + c * 8;
    const u16* gB1 = ebf + (size_t)(bj1 + r) * DD + c * 8;
    const int ldst = wid * 512;   // u16 offset of this wave's chunk

    // frag-read offsets (u16): row = base+l15, chunk q -> slot row*4 + (q^((row>>2)&3))
    const int swz = (q ^ (l15 >> 2)) * 8;
    const int offa = (wm * 64 + l15) * 32 + swz;
    const int offb = (wn * 64 + l15) * 32 + swz;

    // prologue: DMA tile set kt=0 into buffer 0 (3 DMAs per wave)
    async16(gA, &lds_a[0][ldst]);
    async16(gB0, &lds_b[0][0][ldst]);
    async16(gB1, &lds_b[1][0][ldst]);

    f32x4 acc[4][4] = {};
#pragma unroll
    for (int kt = 0; kt < 8; ++kt) {
        const int cur = kt & 1, nxt = cur ^ 1;
        if (kt < 7) {   // prefetch tile set kt+1 (issued BEFORE the wait)
            const int ko = (kt + 1) * 32;
            async16(gA + ko, &lds_a[nxt][ldst]);
            async16(gB0 + ko, &lds_b[0][nxt][ldst]);
            async16(gB1 + ko, &lds_b[1][nxt][ldst]);
            // drain exactly this wave's 3 DMAs for set kt (issued one body ago)
            asm volatile("s_waitcnt vmcnt(3)\n\ts_barrier" ::: "memory");
        } else {
            asm volatile("s_waitcnt vmcnt(0)\n\ts_barrier" ::: "memory");
        }
        short8 af[4], bfr[4];
#pragma unroll
        for (int mi = 0; mi < 4; ++mi)
            af[mi] = *(const short8*)(&lds_a[cur][offa + mi * 512]);
#pragma unroll
        for (int ni = 0; ni < 4; ++ni)
            bfr[ni] = *(const short8*)(&lds_b[tsel][cur][offb + ni * 512]);
#pragma unroll
        for (int mi = 0; mi < 4; ++mi)
#pragma unroll
            for (int ni = 0; ni < 4; ++ni)
                acc[mi][ni] = __builtin_amdgcn_mfma_f32_16x16x32_bf16(
                    af[mi], bfr[ni], acc[mi][ni], 0, 0, 0);
        if (kt < 7) {
            // WAR guard: all waves done reading buf[cur] before body kt+1's DMA clobbers it
            asm volatile("s_waitcnt lgkmcnt(0)\n\ts_barrier" ::: "memory");
        }
    }

    // ---- epilogue: C/D layout col = lane&15, row = q*4 + reg (m89-verified) ----
    int li[4][4];
#pragma unroll
    for (int mi = 0; mi < 4; ++mi) {
        const int4 v = *(const int4*)(labels + bi + wm * 64 + mi * 16 + q * 4);
        li[mi][0] = v.x; li[mi][1] = v.y; li[mi][2] = v.z; li[mi][3] = v.w;
    }
    int lj[4];
#pragma unroll
    for (int ni = 0; ni < 4; ++ni) lj[ni] = labels[bjw + wn * 64 + ni * 16 + l15];

    float mxn[4][4], mnp[4][4];                        // row-side per (mi, r)
    float mxc[4] = {-BIGF, -BIGF, -BIGF, -BIGF};       // col-side per ni
    float mnc[4] = {BIGF, BIGF, BIGF, BIGF};
#pragma unroll
    for (int mi = 0; mi < 4; ++mi)
#pragma unroll
        for (int r2 = 0; r2 < 4; ++r2) { mxn[mi][r2] = -BIGF; mnp[mi][r2] = BIGF; }

#pragma unroll
    for (int mi = 0; mi < 4; ++mi)
#pragma unroll
        for (int ni = 0; ni < 4; ++ni) {
            const int l = lj[ni];
#pragma unroll
            for (int r2 = 0; r2 < 4; ++r2) {
                const float d = acc[mi][ni][r2];
                const bool same = (li[mi][r2] == l);
                const float sneg = same ? -BIGF : d;
                const float spos = same ? d : BIGF;
                mxn[mi][r2] = fmaxf(mxn[mi][r2], sneg);
                mnp[mi][r2] = fminf(mnp[mi][r2], spos);
                mxc[ni] = fmaxf(mxc[ni], sneg);
                mnc[ni] = fminf(mnc[ni], spos);
            }
        }

    // col-side: reduce over q (lanes l15, +16, +32, +48) via shfl_xor 16/32
#pragma unroll
    for (int ni = 0; ni < 4; ++ni) {
        mxc[ni] = fmaxf(mxc[ni], __shfl_xor(mxc[ni], 16));
        mnc[ni] = fminf(mnc[ni], __shfl_xor(mnc[ni], 16));
        mxc[ni] = fmaxf(mxc[ni], __shfl_xor(mxc[ni], 32));
        mnc[ni] = fminf(mnc[ni], __shfl_xor(mnc[ni], 32));
    }
    if (q == 0) {
#pragma unroll
        for (int ni = 0; ni < 4; ++ni) {
            const int col = bjw + wn * 64 + ni * 16 + l15;
            atomicMax(&mxk[col], fkey(mxc[ni]));
            atomicMin(&mnk[col], fkey(mnc[ni]));
        }
    }
    // row-side: 16-lane DPP reduction (xor1, xor2, ror4, ror8) + atomics
#pragma unroll
    for (int mi = 0; mi < 4; ++mi)
#pragma unroll
        for (int r2 = 0; r2 < 4; ++r2) {
            float x = mxn[mi][r2], n = mnp[mi][r2];
            x = fmaxf(x, dpp_mov<0xB1>(x));  n = fminf(n, dpp_mov<0xB1>(n));
            x = fmaxf(x, dpp_mov<0x4E>(x));  n = fminf(n, dpp_mov<0x4E>(n));
            x = fmaxf(x, dpp_mov<0x124>(x)); n = fminf(n, dpp_mov<0x124>(n));
            x = fmaxf(x, dpp_mov<0x128>(x)); n = fminf(n, dpp_mov<0x128>(n));
            if (l15 == 0) {
                const int row = bi + wm * 64 + mi * 16 + q * 4 + r2;
                atomicMax(&mxk[row], fkey(x));
                atomicMin(&mnk[row], fkey(n));
            }
        }
}

// ---------------- kernel 3: per-row loss + mean ----------------
__global__ __launch_bounds__(256) void finalize_kernel(
    const u32* __restrict__ mxk, const u32* __restrict__ mnk,
    const float* __restrict__ sq, float* __restrict__ out) {
    const int i = blockIdx.x * 256 + threadIdx.x;
    const float s = sq[i] + 1.0f;   // sq_i + sq_j, sq_j = 1 +- 1e-7
    const float hn = sqrtf(fmaxf(fmaf(-2.0f, unkey(mxk[i]), s), EPS_PD));
    const float hp = sqrtf(fmaxf(fmaf(-2.0f, unkey(mnk[i]), s), EPS_PD));
    float loss = fmaxf(hp - hn + 1.0f, 0.0f);
    for (int o = 32; o; o >>= 1) loss += __shfl_down(loss, o);
    __shared__ float wsum[4];
    const int lane = threadIdx.x & 63, w = threadIdx.x >> 6;
    if (lane == 0) wsum[w] = loss;
    __syncthreads();
    if (threadIdx.x == 0)
        atomicAdd(out, (wsum[0] + wsum[1] + wsum[2] + wsum[3]) * (1.0f / NS));
}

extern "C" void kernel_launch(void* const* d_in, const int* in_sizes, int n_in,
                              void* d_out, int out_size, void* d_ws, size_t ws_size,
                              hipStream_t stream) {
    const int* labels = (const int*)d_in[0];
    const float* emb = (const float*)d_in[1];
    float* out = (float*)d_out;

    char* ws = (char*)d_ws;
    u16* ebf = (u16*)ws;                                     // 4 MB
    float* sq = (float*)(ws + (size_t)NS * DD * 2);          // 32 KB
    u32* mxk = (u32*)(ws + (size_t)NS * DD * 2 + NS * 4);
    u32* mnk = mxk + NS;

    prep_kernel<<<NS * DD / 4 / 256, 256, 0, stream>>>(emb, ebf, sq, mxk, mnk, out);
    tile_kernel<<<1056, 512, 0, stream>>>(ebf, labels, mxk, mnk);
    finalize_kernel<<<NS / 256, 256, 0, stream>>>(mxk, mnk, sq, out);
}

// Round 15
// 98.023 us; speedup vs baseline: 1.3283x; 1.3283x over previous
//
#include <hip/hip_runtime.h>
#include <hip/hip_bf16.h>

// TripletBatchHardLoss: N=8192, D=256, fp32 embeddings (L2-normalized), int32 labels.
// Normalized -> pdist monotone DECREASING in dot:
//   hard_negative = max dot over negs, hard_positive = min dot over poss (diag dot~1 safe).
// R15 = R13 (double-buffered 2-barrier K-loop, 2080 triangular 128x128 blocks, VGPR-clean
// launch_bounds(256,3)) + ATOMIC-TAIL FIX: epilogue combines per-wave results in LDS and
// issues 8 atomic wave-instructions per block instead of ~160. Rationale: WRITE_SIZE
// ~25-31 MB in every clean round = ~56 B HBM write per atomic lane-op (line write-through);
// the end-of-wave drain of ~40 contended atomic instrs (~300+ cyc each) serialized block
// retirement -- the ~14k cyc/block wall that no K-loop restructure (R3/R8/R12/R13/R14)
// could move.
// VGPR discipline: (256,3)=84 clean; (256,4)=64 spills; (256,5)=48 disaster.
// No __threadfence in wide kernels (R11: per-block fence = per-XCD L2 writeback, +130 us).

#define NS 8192
#define DD 256
#define EPS_PD 1e-12f
#define BIGF 1e30f

typedef unsigned short u16;
typedef unsigned int u32;
typedef short short8 __attribute__((ext_vector_type(8)));
typedef float f32x4 __attribute__((ext_vector_type(4)));

typedef const __attribute__((address_space(1))) u32 glb_u32;
typedef __attribute__((address_space(3))) u32 lds_u32;

__device__ __forceinline__ void async16(const void* g, void* l) {
    __builtin_amdgcn_global_load_lds((glb_u32*)g, (lds_u32*)l, 16, 0, 0);
}

// order-preserving float <-> uint key (unsigned compare == float compare)
__device__ __forceinline__ u32 fkey(float f) {
    u32 b = __float_as_uint(f);
    return (b & 0x80000000u) ? ~b : (b | 0x80000000u);
}
__device__ __forceinline__ float unkey(u32 k) {
    u32 b = (k & 0x80000000u) ? (k ^ 0x80000000u) : ~k;
    return __uint_as_float(b);
}

__device__ __forceinline__ u16 f2bf_rne(float f) {
    u32 b = __float_as_uint(f);
    b += 0x7FFFu + ((b >> 16) & 1u);
    return (u16)(b >> 16);
}

// DPP lane-move within 16-lane rows (reduction groups are exactly DPP rows)
template <int CTRL>
__device__ __forceinline__ float dpp_mov(float x) {
    return __int_as_float(
        __builtin_amdgcn_update_dpp(0, __float_as_int(x), CTRL, 0xF, 0xF, true));
}

// ---------------- kernel 1: fp32 -> bf16, row sum-of-squares, init keys ----------------
__global__ __launch_bounds__(256) void prep_kernel(
    const float* __restrict__ e, u16* __restrict__ ebf, float* __restrict__ sq,
    u32* __restrict__ mxk, u32* __restrict__ mnk, float* __restrict__ out) {
    const int tid = blockIdx.x * 256 + threadIdx.x;   // 2048 blocks
    const int row = tid >> 6, t = tid & 63;           // one wave per row
    float4 v = ((const float4*)(e + (size_t)row * DD))[t];
    ushort4 u;
    u.x = f2bf_rne(v.x); u.y = f2bf_rne(v.y); u.z = f2bf_rne(v.z); u.w = f2bf_rne(v.w);
    ((ushort4*)(ebf + (size_t)row * DD))[t] = u;
    float s = v.x * v.x + v.y * v.y + v.z * v.z + v.w * v.w;
    for (int o = 32; o; o >>= 1) s += __shfl_down(s, o);
    if (t == 0) {
        sq[row] = s;
        mxk[row] = 0u;            // sentinel for unsigned max
        mnk[row] = 0xFFFFFFFFu;   // sentinel for unsigned min
        if (row == 0) out[0] = 0.0f;
    }
}

// ---------------- kernel 2: dbuf triangular dot-GEMM + two-sided masked reduction ---------
__global__ __launch_bounds__(256, 3) void tile_kernel(
    const u16* __restrict__ ebf, const int* __restrict__ labels,
    u32* __restrict__ mxk, u32* __restrict__ mnk) {
    // 2 x (128x32) tiles each; 16B chunk (row,c) at slot row*4 + (c^((row>>2)&3))
    __shared__ __attribute__((aligned(16))) u16 lds_a[2][128 * 32];   // 2 x 8 KB
    __shared__ __attribute__((aligned(16))) u16 lds_b[2][128 * 32];   // 2 x 8 KB

    // decode linear triangle index -> (i <= j)
    const int t = blockIdx.x;
    int j = (int)((sqrtf(8.0f * (float)t + 1.0f) - 1.0f) * 0.5f);
    while ((j + 1) * (j + 2) / 2 <= t) ++j;
    while (j * (j + 1) / 2 > t) --j;
    const int i = t - j * (j + 1) / 2;
    const int bi = i * 128, bj = j * 128;

    const int tid = threadIdx.x;
    const int lane = tid & 63, wid = tid >> 6;
    const int wm = wid >> 1, wn = wid & 1;
    const int l15 = lane & 15, q = lane >> 4;

    // staging: wave wid owns slots [wid*128, wid*128+128) of each 512-slot tile
    const int s0 = wid * 128 + lane, s1 = s0 + 64;
    const int r0 = s0 >> 2, c0 = (s0 & 3) ^ ((r0 >> 2) & 3);
    const int r1 = s1 >> 2, c1 = (s1 & 3) ^ ((r1 >> 2) & 3);
    const u16* gA0 = ebf + (size_t)(bi + r0) * DD + c0 * 8;
    const u16* gA1 = ebf + (size_t)(bi + r1) * DD + c1 * 8;
    const u16* gB0 = ebf + (size_t)(bj + r0) * DD + c0 * 8;
    const u16* gB1 = ebf + (size_t)(bj + r1) * DD + c1 * 8;
    const int ldst0 = wid * 128 * 8, ldst1 = ldst0 + 64 * 8;

    // frag-read offsets (u16 elems): row = base+l15, chunk q -> slot row*4 + (q^((row>>2)&3))
    const int swz = (q ^ (l15 >> 2)) * 8;
    const int offa = (wm * 64 + l15) * 32 + swz;
    const int offb = (wn * 64 + l15) * 32 + swz;

    // prologue: DMA tile 0 into buffer 0
    async16(gA0, &lds_a[0][ldst0]); async16(gA1, &lds_a[0][ldst1]);
    async16(gB0, &lds_b[0][ldst0]); async16(gB1, &lds_b[0][ldst1]);

    f32x4 acc[4][4] = {};
#pragma unroll
    for (int kt = 0; kt < 8; ++kt) {
        const int cur = kt & 1, nxt = cur ^ 1;
        if (kt < 7) {   // prefetch tile kt+1 into the other buffer (issued BEFORE the wait)
            const int ko = (kt + 1) * 32;
            async16(gA0 + ko, &lds_a[nxt][ldst0]); async16(gA1 + ko, &lds_a[nxt][ldst1]);
            async16(gB0 + ko, &lds_b[nxt][ldst0]); async16(gB1 + ko, &lds_b[nxt][ldst1]);
            // drain exactly tile kt's 4 DMAs (issued one full body ago); kt+1 in flight
            asm volatile("s_waitcnt vmcnt(4)\n\ts_barrier" ::: "memory");
        } else {
            asm volatile("s_waitcnt vmcnt(0)\n\ts_barrier" ::: "memory");
        }
        short8 af[4], bfr[4];
#pragma unroll
        for (int mi = 0; mi < 4; ++mi)
            af[mi] = *(const short8*)(&lds_a[cur][offa + mi * 512]);
#pragma unroll
        for (int ni = 0; ni < 4; ++ni)
            bfr[ni] = *(const short8*)(&lds_b[cur][offb + ni * 512]);
#pragma unroll
        for (int mi = 0; mi < 4; ++mi)
#pragma unroll
            for (int ni = 0; ni < 4; ++ni)
                acc[mi][ni] = __builtin_amdgcn_mfma_f32_16x16x32_bf16(
                    af[mi], bfr[ni], acc[mi][ni], 0, 0, 0);
        if (kt < 7) {
            // WAR guard: all waves done reading buf[cur] before body kt+1's DMA clobbers it
            asm volatile("s_waitcnt lgkmcnt(0)\n\ts_barrier" ::: "memory");
        }
    }

    // ---- epilogue: C/D layout col = lane&15, row = q*4 + reg (m89-verified) ----
    int li[4][4];
#pragma unroll
    for (int mi = 0; mi < 4; ++mi) {
        const int4 v = *(const int4*)(labels + bi + wm * 64 + mi * 16 + q * 4);
        li[mi][0] = v.x; li[mi][1] = v.y; li[mi][2] = v.z; li[mi][3] = v.w;
    }
    int lj[4];
#pragma unroll
    for (int ni = 0; ni < 4; ++ni) lj[ni] = labels[bj + wn * 64 + ni * 16 + l15];

    float mxn[4][4], mnp[4][4];                        // row-side per (mi, r)
    float mxc[4] = {-BIGF, -BIGF, -BIGF, -BIGF};       // col-side per ni
    float mnc[4] = {BIGF, BIGF, BIGF, BIGF};
#pragma unroll
    for (int mi = 0; mi < 4; ++mi)
#pragma unroll
        for (int r2 = 0; r2 < 4; ++r2) { mxn[mi][r2] = -BIGF; mnp[mi][r2] = BIGF; }

#pragma unroll
    for (int mi = 0; mi < 4; ++mi)
#pragma unroll
        for (int ni = 0; ni < 4; ++ni) {
            const int l = lj[ni];
#pragma unroll
            for (int r2 = 0; r2 < 4; ++r2) {
                const float d = acc[mi][ni][r2];
                const bool same = (li[mi][r2] == l);
                const float sneg = same ? -BIGF : d;
                const float spos = same ? d : BIGF;
                mxn[mi][r2] = fmaxf(mxn[mi][r2], sneg);
                mnp[mi][r2] = fminf(mnp[mi][r2], spos);
                mxc[ni] = fmaxf(mxc[ni], sneg);
                mnc[ni] = fminf(mnc[ni], spos);
            }
        }

    // col-side: reduce over q (lanes l15, +16, +32, +48) via shfl_xor 16/32
#pragma unroll
    for (int ni = 0; ni < 4; ++ni) {
        mxc[ni] = fmaxf(mxc[ni], __shfl_xor(mxc[ni], 16));
        mnc[ni] = fminf(mnc[ni], __shfl_xor(mnc[ni], 16));
        mxc[ni] = fmaxf(mxc[ni], __shfl_xor(mxc[ni], 32));
        mnc[ni] = fminf(mnc[ni], __shfl_xor(mnc[ni], 32));
    }
    // row-side: 16-lane DPP reduction (xor1, xor2, ror4, ror8)
#pragma unroll
    for (int mi = 0; mi < 4; ++mi)
#pragma unroll
        for (int r2 = 0; r2 < 4; ++r2) {
            float x = mxn[mi][r2], n = mnp[mi][r2];
            x = fmaxf(x, dpp_mov<0xB1>(x));  n = fminf(n, dpp_mov<0xB1>(n));
            x = fmaxf(x, dpp_mov<0x4E>(x));  n = fminf(n, dpp_mov<0x4E>(n));
            x = fmaxf(x, dpp_mov<0x124>(x)); n = fminf(n, dpp_mov<0x124>(n));
            x = fmaxf(x, dpp_mov<0x128>(x)); n = fminf(n, dpp_mov<0x128>(n));
            mxn[mi][r2] = x; mnp[mi][r2] = n;
        }

    // ---- block-level LDS combine -> 8 atomic wave-instrs total ----
    // scratch in lds_a[0] (free: kt=7 used buffer 1; all buf-0 reads retired at the
    // kt=6 trailing barrier). Layout (floats): [0..255] rowmax[row][wn],
    // [256..511] rowmin, [512..767] colmax[col][wm], [768..1023] colmin. 4 KB.
    float* red = (float*)&lds_a[0][0];
    if (l15 == 0) {
#pragma unroll
        for (int mi = 0; mi < 4; ++mi)
#pragma unroll
            for (int r2 = 0; r2 < 4; ++r2) {
                const int rl = wm * 64 + mi * 16 + q * 4 + r2;
                red[rl * 2 + wn] = mxn[mi][r2];
                red[256 + rl * 2 + wn] = mnp[mi][r2];
            }
    }
    if (q == 0) {
#pragma unroll
        for (int ni = 0; ni < 4; ++ni) {
            const int cl = wn * 64 + ni * 16 + l15;
            red[512 + cl * 2 + wm] = mxc[ni];
            red[768 + cl * 2 + wm] = mnc[ni];
        }
    }
    __syncthreads();
    if (tid < 128) {
        const float mx = fmaxf(red[tid * 2], red[tid * 2 + 1]);
        const float mn = fminf(red[256 + tid * 2], red[256 + tid * 2 + 1]);
        atomicMax(&mxk[bi + tid], fkey(mx));
        atomicMin(&mnk[bi + tid], fkey(mn));
    } else {
        const int c = tid - 128;
        const float mx = fmaxf(red[512 + c * 2], red[512 + c * 2 + 1]);
        const float mn = fminf(red[768 + c * 2], red[768 + c * 2 + 1]);
        atomicMax(&mxk[bj + c], fkey(mx));
        atomicMin(&mnk[bj + c], fkey(mn));
    }
}

// ---------------- kernel 3: per-row loss + mean ----------------
__global__ __launch_bounds__(256) void finalize_kernel(
    const u32* __restrict__ mxk, const u32* __restrict__ mnk,
    const float* __restrict__ sq, float* __restrict__ out) {
    const int i = blockIdx.x * 256 + threadIdx.x;
    const float s = sq[i] + 1.0f;   // sq_i + sq_j, sq_j = 1 +- 1e-7
    const float hn = sqrtf(fmaxf(fmaf(-2.0f, unkey(mxk[i]), s), EPS_PD));
    const float hp = sqrtf(fmaxf(fmaf(-2.0f, unkey(mnk[i]), s), EPS_PD));
    float loss = fmaxf(hp - hn + 1.0f, 0.0f);
    for (int o = 32; o; o >>= 1) loss += __shfl_down(loss, o);
    __shared__ float wsum[4];
    const int lane = threadIdx.x & 63, w = threadIdx.x >> 6;
    if (lane == 0) wsum[w] = loss;
    __syncthreads();
    if (threadIdx.x == 0)
        atomicAdd(out, (wsum[0] + wsum[1] + wsum[2] + wsum[3]) * (1.0f / NS));
}

extern "C" void kernel_launch(void* const* d_in, const int* in_sizes, int n_in,
                              void* d_out, int out_size, void* d_ws, size_t ws_size,
                              hipStream_t stream) {
    const int* labels = (const int*)d_in[0];
    const float* emb = (const float*)d_in[1];
    float* out = (float*)d_out;

    char* ws = (char*)d_ws;
    u16* ebf = (u16*)ws;                                     // 4 MB
    float* sq = (float*)(ws + (size_t)NS * DD * 2);          // 32 KB
    u32* mxk = (u32*)(ws + (size_t)NS * DD * 2 + NS * 4);
    u32* mnk = mxk + NS;

    prep_kernel<<<NS * DD / 4 / 256, 256, 0, stream>>>(emb, ebf, sq, mxk, mnk, out);
    tile_kernel<<<2080, 256, 0, stream>>>(ebf, labels, mxk, mnk);
    finalize_kernel<<<NS / 256, 256, 0, stream>>>(mxk, mnk, sq, out);
}